// Round 1
// baseline (1035.635 us; speedup 1.0000x reference)
//
#include <hip/hip_runtime.h>
#include <stdint.h>
#include <stddef.h>

// ---------------------------------------------------------------------------
// MixtralAttention on MI355X (gfx950).
// fp32 in/out, bf16 MFMA compute. B=2,S=2048,H=4096,NH=32,NKV=8,D=128
// ws layout: qkv [4096][6144] bf16 (48MB) ; wT 32MB ; hiddenB 32MB (guarded)
// Attention output written in-place into the q-slot of qkv.
// ---------------------------------------------------------------------------

typedef short short8 __attribute__((ext_vector_type(8)));
typedef float f32x4  __attribute__((ext_vector_type(4)));

__device__ __forceinline__ float bf2f(short s) {
    union { uint32_t u; float f; } v;
    v.u = ((uint32_t)(uint16_t)s) << 16;
    return v.f;
}
__device__ __forceinline__ short f2bf(float f) {
    union { float f; uint32_t u; } v;
    v.f = f;
    uint32_t u = v.u;
    uint32_t r = (u + 0x7FFFu + ((u >> 16) & 1u)) >> 16;  // RNE
    return (short)(uint16_t)r;
}
__device__ __forceinline__ short8 ldcvt8(const float* p) {
    float4 a = *(const float4*)p;
    float4 b = *(const float4*)(p + 4);
    short8 r;
    r[0] = f2bf(a.x); r[1] = f2bf(a.y); r[2] = f2bf(a.z); r[3] = f2bf(a.w);
    r[4] = f2bf(b.x); r[5] = f2bf(b.y); r[6] = f2bf(b.z); r[7] = f2bf(b.w);
    return r;
}
__device__ __forceinline__ void st_out(short* p, float v) { *p = f2bf(v); }
__device__ __forceinline__ void st_out(float* p, float v) { *p = v; }

#define GLDS16(g, l) __builtin_amdgcn_global_load_lds( \
    (const __attribute__((address_space(1))) void*)(g), \
    (__attribute__((address_space(3))) void*)(l), 16, 0, 0)

// ---------------------------------------------------------------------------
// fp32 -> bf16 bulk convert (grid-stride, 8 elems/thread/iter)
// ---------------------------------------------------------------------------
__global__ __launch_bounds__(256)
void cvt_bf16(const float* __restrict__ in, short* __restrict__ out, int n8)
{
    int i = blockIdx.x * 256 + threadIdx.x;
    int stride = gridDim.x * 256;
    for (; i < n8; i += stride)
        *(short8*)(out + (size_t)i * 8) = ldcvt8(in + (size_t)i * 8);
}

// ---------------------------------------------------------------------------
// Tiled transpose + fp32->bf16 convert: in[R][ldin] (slice width Cs) -> out[Cs][R]
// ---------------------------------------------------------------------------
__global__ __launch_bounds__(256)
void transpose_cvt(const float* __restrict__ in, int ldin,
                   short* __restrict__ out, int R, int Cs)
{
    __shared__ short tile[64][72];
    const int bc = blockIdx.x * 64;   // col base (input)
    const int br = blockIdx.y * 64;   // row base (input)
    const int tid = threadIdx.x;
    const int r  = tid >> 2;          // 0..63
    const int c0 = (tid & 3) * 16;

    const float* src = in + (size_t)(br + r) * ldin + bc + c0;
#pragma unroll
    for (int i = 0; i < 4; i++) {
        float4 v = *(const float4*)(src + 4 * i);
        tile[c0 + 4 * i + 0][r] = f2bf(v.x);
        tile[c0 + 4 * i + 1][r] = f2bf(v.y);
        tile[c0 + 4 * i + 2][r] = f2bf(v.z);
        tile[c0 + 4 * i + 3][r] = f2bf(v.w);
    }
    __syncthreads();

    short* dst = out + (size_t)(bc + r) * R + br + c0;
    *(short8*)(dst)     = *(const short8*)(&tile[r][c0]);
    *(short8*)(dst + 8) = *(const short8*)(&tile[r][c0 + 8]);
}

// ---------------------------------------------------------------------------
// Staging helpers. LDS tile layout: T[128][64] bf16, unpadded, XOR-swizzled:
// element (row, chunk16B c_log) lives at byte row*128 + (c_log ^ (row&7))*16.
// ---------------------------------------------------------------------------
// fp32 source: vector load + convert + ds_write_b128 (per-lane scatter ok)
__device__ __forceinline__ void stage_tile(const float* __restrict__ Ab, size_t lda,
                                           int kb, short* T, int tid)
{
    const int aRow = tid >> 3;        // 0..31 (+32*j)
    const int aChk = tid & 7;
#pragma unroll
    for (int j = 0; j < 4; j++) {
        int row = aRow + 32 * j;
        short8 v = ldcvt8(Ab + (size_t)row * lda + kb + aChk * 8);
        *(short8*)(&T[row * 64 + ((aChk ^ (row & 7)) * 8)]) = v;
    }
}
// bf16 source: global_load_lds width 16 (LDS dest = wave base + lane*16)
__device__ __forceinline__ void stage_tile(const short* __restrict__ Ab, size_t lda,
                                           int kb, short* T, int tid)
{
    const int lane = tid & 63;
    const int wave = tid >> 6;
    const int sRow = lane >> 3;       // 0..7
    const int sPhy = lane & 7;
    const int logc = sPhy ^ sRow;     // (row&7)==sRow for all j
#pragma unroll
    for (int j = 0; j < 4; j++) {
        int row = wave * 32 + j * 8 + sRow;
        const short* g = Ab + (size_t)row * lda + kb + logc * 8;
        GLDS16(g, T + (size_t)(wave * 32 + j * 8) * 64);
    }
}

// ---------------------------------------------------------------------------
// GEMM: C[M,N] = A[M,K] @ Bt[N,K]^T.  A: fp32 (convert) or bf16; Bt bf16
// pre-transposed [N][K]; C fp32 or bf16 with row stride ldc.
// Block 256 = 4 waves (2x2), tile 128x128, BK=64, mfma 16x16x32 bf16.
// XCD-aware bijective block swizzle (grids are multiples of 8).
// ---------------------------------------------------------------------------
template <typename AT, typename CT>
__global__ __launch_bounds__(256, 2)
void gemm_tn(const AT* __restrict__ A, int lda, const short* __restrict__ Bt,
             CT* __restrict__ C, int ldc, int M, int N, int K)
{
    __shared__ __align__(16) short As[128 * 64];
    __shared__ __align__(16) short Bs[128 * 64];

    const int tid  = threadIdx.x;
    const int lane = tid & 63;
    const int wave = tid >> 6;
    const int l16  = lane & 15;
    const int quad = lane >> 4;
    const int wm   = wave >> 1;
    const int wn   = wave & 1;

    // XCD swizzle: contiguous chunk of the row-major (mb,nb) space per XCD
    const int nbx = gridDim.x;
    const int nwg = nbx * gridDim.y;
    int wg = blockIdx.y * nbx + blockIdx.x;
    if ((nwg & 7) == 0) {
        const int cpx = nwg >> 3;
        wg = (wg & 7) * cpx + (wg >> 3);
    }
    const int mb = wg / nbx;
    const int nb = wg - mb * nbx;

    const AT*    Ab = A  + (size_t)mb * 128 * lda;
    const short* Bb = Bt + (size_t)nb * 128 * K;

    f32x4 acc[4][4];
#pragma unroll
    for (int i = 0; i < 4; i++)
#pragma unroll
        for (int j = 0; j < 4; j++) acc[i][j] = {0.f, 0.f, 0.f, 0.f};

    for (int kb = 0; kb < K; kb += 64) {
        __syncthreads();
        stage_tile(Ab, (size_t)lda, kb, As, tid);
        stage_tile(Bb, (size_t)K,   kb, Bs, tid);
        __syncthreads();

#pragma unroll
        for (int ks = 0; ks < 2; ks++) {
            short8 af[4], bf[4];
#pragma unroll
            for (int t = 0; t < 4; t++) {
                int ar = wm * 64 + t * 16 + l16;
                int br = wn * 64 + t * 16 + l16;
                af[t] = *(const short8*)(&As[ar * 64 + (((ks * 4 + quad) ^ (ar & 7)) * 8)]);
                bf[t] = *(const short8*)(&Bs[br * 64 + (((ks * 4 + quad) ^ (br & 7)) * 8)]);
            }
#pragma unroll
            for (int mt = 0; mt < 4; mt++)
#pragma unroll
                for (int nt = 0; nt < 4; nt++)
                    acc[mt][nt] = __builtin_amdgcn_mfma_f32_16x16x32_bf16(
                        af[mt], bf[nt], acc[mt][nt], 0, 0, 0);
        }
    }

    // epilogue: C/D layout row = quad*4+reg, col = lane&15
#pragma unroll
    for (int mt = 0; mt < 4; mt++)
#pragma unroll
        for (int nt = 0; nt < 4; nt++)
#pragma unroll
            for (int r = 0; r < 4; r++) {
                int row = mb * 128 + wm * 64 + mt * 16 + quad * 4 + r;
                int col = nb * 128 + wn * 64 + nt * 16 + l16;
                st_out(&C[(size_t)row * ldc + col], acc[mt][nt][r]);
            }
}

// ---------------------------------------------------------------------------
// RoPE (neox) in-place on q (32 heads) and k (8 heads) in bf16 qkv ws.
// Per thread: d = tid&63 is loop-invariant -> hoist trig.
// ---------------------------------------------------------------------------
__global__ __launch_bounds__(256)
void rope_kernel(const int* __restrict__ positions, short* __restrict__ qkv)
{
    const int tok = blockIdx.x;
    const float fp = (float)positions[tok];
    short* base = qkv + (size_t)tok * 6144;
    const float c0 = 0.14391156516f;  // ln(10000)/64

    const int d = threadIdx.x & 63;
    const float inv = __expf(-(float)d * c0);
    const float ang = fp * inv;
    float s, c;
    __sincosf(ang, &s, &c);

    for (int head = threadIdx.x >> 6; head < 40; head += 4) {
        int off = (head < 32) ? head * 128 : 4096 + (head - 32) * 128;
        float x1 = bf2f(base[off + d]);
        float x2 = bf2f(base[off + d + 64]);
        base[off + d]      = f2bf(x1 * c - x2 * s);
        base[off + d + 64] = f2bf(x2 * c + x1 * s);
    }
}

// ---------------------------------------------------------------------------
// Causal GQA flash attention; output written IN-PLACE into the q-slot.
// Grid: b(2) x h(32) x qb(32) = 2048 blocks. Block: 4 waves x 16 q-rows.
// ---------------------------------------------------------------------------
__global__ __launch_bounds__(256, 2)
void attn_kernel(short* __restrict__ qkv)
{
    __shared__ __align__(16) short Ks[64][136];
    __shared__ __align__(16) short Vt[128][72];
    __shared__ __align__(16) short Pw[4][16][72];

    const int blk = blockIdx.x;
    const int qb  = blk & 31;
    const int h   = (blk >> 5) & 31;
    const int b   = blk >> 10;
    const int hk  = h >> 2;

    const int tid  = threadIdx.x;
    const int lane = tid & 63;
    const int wave = tid >> 6;
    const int l16  = lane & 15;
    const int quad = lane >> 4;

    const size_t ld = 6144;
    const short* Kbase = qkv + (size_t)b * 2048 * ld + 4096 + hk * 128;
    const short* Vbase = Kbase + 1024;

    // Q fragments: A[m=l16][k = ks*32 + quad*8 + j] — fully read before K-loop
    short8 qf[4];
    {
        const short* Qp = qkv + (size_t)(b * 2048 + qb * 64 + wave * 16 + l16) * ld + h * 128;
#pragma unroll
        for (int ks = 0; ks < 4; ks++)
            qf[ks] = *(const short8*)(Qp + ks * 32 + quad * 8);
    }

    f32x4 oacc[8];
#pragma unroll
    for (int g = 0; g < 8; g++) oacc[g] = {0.f, 0.f, 0.f, 0.f};
    float mrow[4] = {-1e30f, -1e30f, -1e30f, -1e30f};
    float lrow[4] = {0.f, 0.f, 0.f, 0.f};
    const float scale = 0.08838834764831845f;  // 1/sqrt(128)

    const int kRow = tid >> 4;          // + 16*j
    const int kCol = (tid & 15) * 8;
    const int vRow = tid & 63;
    const int vN8  = tid >> 6;          // + 4*j

    for (int kt = 0; kt <= qb; kt++) {
        __syncthreads();
#pragma unroll
        for (int j = 0; j < 4; j++) {
            int row = kRow + 16 * j;
            short8 v = *(const short8*)(Kbase + (size_t)(kt * 64 + row) * ld + kCol);
            *(short8*)(&Ks[row][kCol]) = v;
        }
#pragma unroll
        for (int j = 0; j < 4; j++) {
            int n = (vN8 + 4 * j) * 8;
            short8 v = *(const short8*)(Vbase + (size_t)(kt * 64 + vRow) * ld + n);
#pragma unroll
            for (int i = 0; i < 8; i++) Vt[n + i][vRow] = v[i];
        }
        __syncthreads();

        f32x4 sacc[4];
#pragma unroll
        for (int g = 0; g < 4; g++) {
            sacc[g] = {0.f, 0.f, 0.f, 0.f};
#pragma unroll
            for (int ks = 0; ks < 4; ks++) {
                short8 kf = *(const short8*)(&Ks[l16 + 16 * g][ks * 32 + quad * 8]);
                sacc[g] = __builtin_amdgcn_mfma_f32_16x16x32_bf16(qf[ks], kf, sacc[g], 0, 0, 0);
            }
        }

        const int srow_base = qb * 64 + wave * 16 + quad * 4;
        const bool diag = (kt == qb);
        float sv[4][4];
#pragma unroll
        for (int g = 0; g < 4; g++)
#pragma unroll
            for (int r = 0; r < 4; r++) {
                float x = sacc[g][r] * scale;
                if (diag) {
                    int t = kt * 64 + g * 16 + l16;
                    if (t > srow_base + r) x = -1e30f;
                }
                sv[g][r] = x;
            }
#pragma unroll
        for (int r = 0; r < 4; r++) {
            float mx = fmaxf(fmaxf(sv[0][r], sv[1][r]), fmaxf(sv[2][r], sv[3][r]));
#pragma unroll
            for (int off = 1; off < 16; off <<= 1)
                mx = fmaxf(mx, __shfl_xor(mx, off, 64));
            float mn = fmaxf(mrow[r], mx);
            float al = __expf(mrow[r] - mn);
            float rs = 0.f;
#pragma unroll
            for (int g = 0; g < 4; g++) {
                float p = __expf(sv[g][r] - mn);
                sv[g][r] = p;
                rs += p;
            }
#pragma unroll
            for (int off = 1; off < 16; off <<= 1)
                rs += __shfl_xor(rs, off, 64);
            lrow[r] = lrow[r] * al + rs;
            mrow[r] = mn;
#pragma unroll
            for (int gd = 0; gd < 8; gd++) oacc[gd][r] *= al;
        }

#pragma unroll
        for (int g = 0; g < 4; g++)
#pragma unroll
            for (int r = 0; r < 4; r++)
                Pw[wave][quad * 4 + r][l16 + 16 * g] = f2bf(sv[g][r]);
        __syncthreads();

#pragma unroll
        for (int ks = 0; ks < 2; ks++) {
            short8 af = *(const short8*)(&Pw[wave][l16][ks * 32 + quad * 8]);
#pragma unroll
            for (int gd = 0; gd < 8; gd++) {
                short8 vf = *(const short8*)(&Vt[l16 + 16 * gd][ks * 32 + quad * 8]);
                oacc[gd] = __builtin_amdgcn_mfma_f32_16x16x32_bf16(af, vf, oacc[gd], 0, 0, 0);
            }
        }
    }

    // epilogue: write O in-place into the q-slot (ld 6144)
    const int srow_base = qb * 64 + wave * 16 + quad * 4;
#pragma unroll
    for (int r = 0; r < 4; r++) {
        float inv = 1.0f / lrow[r];
        size_t rowoff = (size_t)(b * 2048 + srow_base + r) * ld + h * 128;
#pragma unroll
        for (int gd = 0; gd < 8; gd++)
            qkv[rowoff + gd * 16 + l16] = f2bf(oacc[gd][r] * inv);
    }
}

// ---------------------------------------------------------------------------
// launcher
// ---------------------------------------------------------------------------
extern "C" void kernel_launch(void* const* d_in, const int* in_sizes, int n_in,
                              void* d_out, int out_size, void* d_ws, size_t ws_size,
                              hipStream_t stream)
{
    const int*   positions = (const int*)d_in[0];
    const float* hidden    = (const float*)d_in[1];  // fp32 [4096, 4096]
    const float* w_qkv     = (const float*)d_in[2];  // fp32 [4096, 6144]
    const float* w_o       = (const float*)d_in[3];  // fp32 [4096, 4096]
    float* out = (float*)d_out;                      // fp32 [4096, 4096]

    short* qkv = (short*)d_ws;                       // bf16 [4096][6144], 48 MB
    short* wT  = qkv + (size_t)4096 * 6144;          // 32 MB transpose buffer
    short* hB  = wT  + (size_t)4096 * 4096;          // 32 MB hidden bf16 (optional)

    const size_t need = ((size_t)4096 * 6144 + (size_t)4096 * 4096 * 2) * sizeof(short);
    const bool cvtA = (ws_size >= need);

    // 1) QKV projection in two N-chunks of 3072 (wT reused, stream-ordered)
    if (cvtA) {
        cvt_bf16<<<2048, 256, 0, stream>>>(hidden, hB, 4096 * 4096 / 8);
        for (int c = 0; c < 2; c++) {
            transpose_cvt<<<dim3(48, 64), 256, 0, stream>>>(
                w_qkv + c * 3072, 6144, wT, 4096, 3072);
            gemm_tn<short, short><<<dim3(24, 32), 256, 0, stream>>>(
                hB, 4096, wT, qkv + c * 3072, 6144, 4096, 3072, 4096);
        }
    } else {
        for (int c = 0; c < 2; c++) {
            transpose_cvt<<<dim3(48, 64), 256, 0, stream>>>(
                w_qkv + c * 3072, 6144, wT, 4096, 3072);
            gemm_tn<float, short><<<dim3(24, 32), 256, 0, stream>>>(
                hidden, 4096, wT, qkv + c * 3072, 6144, 4096, 3072, 4096);
        }
    }
    // 2) RoPE in place on q,k
    rope_kernel<<<4096, 256, 0, stream>>>(positions, qkv);
    // 3) causal GQA flash attention (output -> q-slot)
    attn_kernel<<<2048, 256, 0, stream>>>(qkv);
    // 4) output projection: A = q-slot of qkv (lda 6144), B = w_o^T
    transpose_cvt<<<dim3(64, 64), 256, 0, stream>>>(w_o, 4096, wT, 4096, 4096);
    gemm_tn<short, float><<<dim3(32, 32), 256, 0, stream>>>(
        qkv, 6144, wT, out, 4096, 4096, 4096, 4096);
}

// Round 2
// 920.724 us; speedup vs baseline: 1.1248x; 1.1248x over previous
//
#include <hip/hip_runtime.h>
#include <stdint.h>
#include <stddef.h>

// ---------------------------------------------------------------------------
// MixtralAttention on MI355X (gfx950).
// fp32 in/out, bf16 MFMA compute. B=2,S=2048,H=4096,NH=32,NKV=8,D=128
// ws layout: qkv [4096][6144] bf16 (48MB) ; wT 32MB (also holds vT 8MB) ;
//            hiddenB 32MB (guarded)
// Attention output written in-place into the q-slot of qkv.
// ---------------------------------------------------------------------------

typedef short short8 __attribute__((ext_vector_type(8)));
typedef float f32x4  __attribute__((ext_vector_type(4)));

__device__ __forceinline__ float bf2f(short s) {
    union { uint32_t u; float f; } v;
    v.u = ((uint32_t)(uint16_t)s) << 16;
    return v.f;
}
__device__ __forceinline__ short f2bf(float f) {
    union { float f; uint32_t u; } v;
    v.f = f;
    uint32_t u = v.u;
    uint32_t r = (u + 0x7FFFu + ((u >> 16) & 1u)) >> 16;  // RNE
    return (short)(uint16_t)r;
}
__device__ __forceinline__ short8 ldcvt8(const float* p) {
    float4 a = *(const float4*)p;
    float4 b = *(const float4*)(p + 4);
    short8 r;
    r[0] = f2bf(a.x); r[1] = f2bf(a.y); r[2] = f2bf(a.z); r[3] = f2bf(a.w);
    r[4] = f2bf(b.x); r[5] = f2bf(b.y); r[6] = f2bf(b.z); r[7] = f2bf(b.w);
    return r;
}
__device__ __forceinline__ void st_out(short* p, float v) { *p = f2bf(v); }
__device__ __forceinline__ void st_out(float* p, float v) { *p = v; }

#define GLDS16(g, l) __builtin_amdgcn_global_load_lds( \
    (const __attribute__((address_space(1))) void*)(g), \
    (__attribute__((address_space(3))) void*)(l), 16, 0, 0)

// ---------------------------------------------------------------------------
// fp32 -> bf16 bulk convert (grid-stride, 8 elems/thread/iter)
// ---------------------------------------------------------------------------
__global__ __launch_bounds__(256)
void cvt_bf16(const float* __restrict__ in, short* __restrict__ out, int n8)
{
    int i = blockIdx.x * 256 + threadIdx.x;
    int stride = gridDim.x * 256;
    for (; i < n8; i += stride)
        *(short8*)(out + (size_t)i * 8) = ldcvt8(in + (size_t)i * 8);
}

// ---------------------------------------------------------------------------
// Tiled transpose + fp32->bf16 convert: in[R][ldin] (slice width Cs) -> out[Cs][R]
// ---------------------------------------------------------------------------
__global__ __launch_bounds__(256)
void transpose_cvt(const float* __restrict__ in, int ldin,
                   short* __restrict__ out, int R, int Cs)
{
    __shared__ short tile[64][72];
    const int bc = blockIdx.x * 64;   // col base (input)
    const int br = blockIdx.y * 64;   // row base (input)
    const int tid = threadIdx.x;
    const int r  = tid >> 2;          // 0..63
    const int c0 = (tid & 3) * 16;

    const float* src = in + (size_t)(br + r) * ldin + bc + c0;
#pragma unroll
    for (int i = 0; i < 4; i++) {
        float4 v = *(const float4*)(src + 4 * i);
        tile[c0 + 4 * i + 0][r] = f2bf(v.x);
        tile[c0 + 4 * i + 1][r] = f2bf(v.y);
        tile[c0 + 4 * i + 2][r] = f2bf(v.z);
        tile[c0 + 4 * i + 3][r] = f2bf(v.w);
    }
    __syncthreads();

    short* dst = out + (size_t)(bc + r) * R + br + c0;
    *(short8*)(dst)     = *(const short8*)(&tile[r][c0]);
    *(short8*)(dst + 8) = *(const short8*)(&tile[r][c0 + 8]);
}

// ---------------------------------------------------------------------------
// V head-transpose: qkv v-slot [4096 tok][8 hk x 128 d] -> vT[b][hk][128 d][2048 tok]
// ---------------------------------------------------------------------------
__global__ __launch_bounds__(256)
void transpose_v(const short* __restrict__ qkv, short* __restrict__ vT)
{
    __shared__ short tile[64][72];
    const int bh = blockIdx.z;        // b*8 + hk
    const int b  = bh >> 3;
    const int hk = bh & 7;
    const int s0 = blockIdx.x * 64;
    const int d0 = blockIdx.y * 64;
    const int tid = threadIdx.x;
    const int r  = tid >> 2;          // 0..63
    const int c0 = (tid & 3) * 16;

    const short* src = qkv + (size_t)(b * 2048 + s0 + r) * 6144 + 5120 + hk * 128 + d0 + c0;
    short8 v0 = *(const short8*)(src);
    short8 v1 = *(const short8*)(src + 8);
#pragma unroll
    for (int i = 0; i < 8; i++) tile[c0 + i][r] = v0[i];
#pragma unroll
    for (int i = 0; i < 8; i++) tile[c0 + 8 + i][r] = v1[i];
    __syncthreads();

    short* dst = vT + ((size_t)bh * 128 + d0 + r) * 2048 + s0 + c0;
    *(short8*)(dst)     = *(const short8*)(&tile[r][c0]);
    *(short8*)(dst + 8) = *(const short8*)(&tile[r][c0 + 8]);
}

// ---------------------------------------------------------------------------
// Staging helpers for GEMM. LDS tile layout: T[128][64] bf16, XOR-swizzled:
// element (row, chunk16B c_log) lives at byte row*128 + (c_log ^ (row&7))*16.
// ---------------------------------------------------------------------------
__device__ __forceinline__ void stage_tile(const float* __restrict__ Ab, size_t lda,
                                           int kb, short* T, int tid)
{
    const int aRow = tid >> 3;        // 0..31 (+32*j)
    const int aChk = tid & 7;
#pragma unroll
    for (int j = 0; j < 4; j++) {
        int row = aRow + 32 * j;
        short8 v = ldcvt8(Ab + (size_t)row * lda + kb + aChk * 8);
        *(short8*)(&T[row * 64 + ((aChk ^ (row & 7)) * 8)]) = v;
    }
}
__device__ __forceinline__ void stage_tile(const short* __restrict__ Ab, size_t lda,
                                           int kb, short* T, int tid)
{
    const int lane = tid & 63;
    const int wave = tid >> 6;
    const int sRow = lane >> 3;       // 0..7
    const int sPhy = lane & 7;
    const int logc = sPhy ^ sRow;     // (row&7)==sRow for all j
#pragma unroll
    for (int j = 0; j < 4; j++) {
        int row = wave * 32 + j * 8 + sRow;
        const short* g = Ab + (size_t)row * lda + kb + logc * 8;
        GLDS16(g, T + (size_t)(wave * 32 + j * 8) * 64);
    }
}

// ---------------------------------------------------------------------------
// GEMM: C[M,N] = A[M,K] @ Bt[N,K]^T.  A: fp32 (convert) or bf16; Bt bf16
// pre-transposed [N][K]; C fp32 or bf16 with row stride ldc.
// Block 256 = 4 waves (2x2), tile 128x128, BK=64, mfma 16x16x32 bf16.
// ---------------------------------------------------------------------------
template <typename AT, typename CT>
__global__ __launch_bounds__(256, 2)
void gemm_tn(const AT* __restrict__ A, int lda, const short* __restrict__ Bt,
             CT* __restrict__ C, int ldc, int M, int N, int K)
{
    __shared__ __align__(16) short As[128 * 64];
    __shared__ __align__(16) short Bs[128 * 64];

    const int tid  = threadIdx.x;
    const int lane = tid & 63;
    const int wave = tid >> 6;
    const int l16  = lane & 15;
    const int quad = lane >> 4;
    const int wm   = wave >> 1;
    const int wn   = wave & 1;

    // XCD swizzle: contiguous chunk of the row-major (mb,nb) space per XCD
    const int nbx = gridDim.x;
    const int nwg = nbx * gridDim.y;
    int wg = blockIdx.y * nbx + blockIdx.x;
    if ((nwg & 7) == 0) {
        const int cpx = nwg >> 3;
        wg = (wg & 7) * cpx + (wg >> 3);
    }
    const int mb = wg / nbx;
    const int nb = wg - mb * nbx;

    const AT*    Ab = A  + (size_t)mb * 128 * lda;
    const short* Bb = Bt + (size_t)nb * 128 * K;

    f32x4 acc[4][4];
#pragma unroll
    for (int i = 0; i < 4; i++)
#pragma unroll
        for (int j = 0; j < 4; j++) acc[i][j] = {0.f, 0.f, 0.f, 0.f};

    for (int kb = 0; kb < K; kb += 64) {
        __syncthreads();
        stage_tile(Ab, (size_t)lda, kb, As, tid);
        stage_tile(Bb, (size_t)K,   kb, Bs, tid);
        __syncthreads();

#pragma unroll
        for (int ks = 0; ks < 2; ks++) {
            short8 af[4], bf[4];
#pragma unroll
            for (int t = 0; t < 4; t++) {
                int ar = wm * 64 + t * 16 + l16;
                int br = wn * 64 + t * 16 + l16;
                af[t] = *(const short8*)(&As[ar * 64 + (((ks * 4 + quad) ^ (ar & 7)) * 8)]);
                bf[t] = *(const short8*)(&Bs[br * 64 + (((ks * 4 + quad) ^ (br & 7)) * 8)]);
            }
#pragma unroll
            for (int mt = 0; mt < 4; mt++)
#pragma unroll
                for (int nt = 0; nt < 4; nt++)
                    acc[mt][nt] = __builtin_amdgcn_mfma_f32_16x16x32_bf16(
                        af[mt], bf[nt], acc[mt][nt], 0, 0, 0);
        }
    }

#pragma unroll
    for (int mt = 0; mt < 4; mt++)
#pragma unroll
        for (int nt = 0; nt < 4; nt++)
#pragma unroll
            for (int r = 0; r < 4; r++) {
                int row = mb * 128 + wm * 64 + mt * 16 + quad * 4 + r;
                int col = nb * 128 + wn * 64 + nt * 16 + l16;
                st_out(&C[(size_t)row * ldc + col], acc[mt][nt][r]);
            }
}

// ---------------------------------------------------------------------------
// RoPE (neox) in-place on q (32 heads) and k (8 heads) in bf16 qkv ws.
// ---------------------------------------------------------------------------
__global__ __launch_bounds__(256)
void rope_kernel(const int* __restrict__ positions, short* __restrict__ qkv)
{
    const int tok = blockIdx.x;
    const float fp = (float)positions[tok];
    short* base = qkv + (size_t)tok * 6144;
    const float c0 = 0.14391156516f;  // ln(10000)/64

    const int d = threadIdx.x & 63;
    const float inv = __expf(-(float)d * c0);
    const float ang = fp * inv;
    float s, c;
    __sincosf(ang, &s, &c);

    for (int head = threadIdx.x >> 6; head < 40; head += 4) {
        int off = (head < 32) ? head * 128 : 4096 + (head - 32) * 128;
        float x1 = bf2f(base[off + d]);
        float x2 = bf2f(base[off + d + 64]);
        base[off + d]      = f2bf(x1 * c - x2 * s);
        base[off + d + 64] = f2bf(x2 * c + x1 * s);
    }
}

// ---------------------------------------------------------------------------
// Causal GQA flash attention; output written IN-PLACE into the q-slot.
// Grid: b(2) x h(32) x qb(32) = 2048 blocks. Block: 4 waves x 16 q-rows.
// Double-buffered K/V tiles via global_load_lds; ONE barrier per K-tile.
// K LDS: [64 tok][128 d], chunk16B swizzle c^(row&15).
// V LDS: [128 d][64 tok] from pre-transposed vT, chunk swizzle c^(row&7).
// ---------------------------------------------------------------------------
__global__ __launch_bounds__(256, 2)
void attn_kernel(short* __restrict__ qkv, const short* __restrict__ vT)
{
    __shared__ __align__(16) short Ks[2][64 * 128];
    __shared__ __align__(16) short Vs[2][128 * 64];
    __shared__ __align__(16) short Pw[4][16][72];

    const int blk = blockIdx.x;
    const int qb  = blk & 31;
    const int h   = (blk >> 5) & 31;
    const int b   = blk >> 10;
    const int hk  = h >> 2;

    const int tid  = threadIdx.x;
    const int lane = tid & 63;
    const int wave = tid >> 6;
    const int l16  = lane & 15;
    const int quad = lane >> 4;

    const size_t ld = 6144;
    const short* Kbase = qkv + (size_t)b * 2048 * ld + 4096 + hk * 128;
    const short* Vtb   = vT + (size_t)(b * 8 + hk) * 128 * 2048;

    // Q fragments: A[m=l16][k = ks*32 + quad*8 + j]
    short8 qf[4];
    {
        const short* Qp = qkv + (size_t)(b * 2048 + qb * 64 + wave * 16 + l16) * ld + h * 128;
#pragma unroll
        for (int ks = 0; ks < 4; ks++)
            qf[ks] = *(const short8*)(Qp + ks * 32 + quad * 8);
    }

    f32x4 oacc[8];
#pragma unroll
    for (int g = 0; g < 8; g++) oacc[g] = {0.f, 0.f, 0.f, 0.f};
    float mrow[4] = {-1e30f, -1e30f, -1e30f, -1e30f};
    float lrow[4] = {0.f, 0.f, 0.f, 0.f};
    const float scale = 0.08838834764831845f;  // 1/sqrt(128)

    const int sRowK = lane >> 4;   // 0..3
    const int sPhyK = lane & 15;
    const int sRowV = lane >> 3;   // 0..7
    const int sPhyV = lane & 7;

    auto stageK = [&](int buf, int kt) {
#pragma unroll
        for (int i = 0; i < 4; i++) {
            int row  = wave * 16 + i * 4 + sRowK;
            int logc = sPhyK ^ (row & 15);
            GLDS16(Kbase + (size_t)(kt * 64 + row) * ld + logc * 8,
                   &Ks[buf][(wave * 16 + i * 4) * 128]);
        }
    };
    auto stageV = [&](int buf, int kt) {
#pragma unroll
        for (int i = 0; i < 4; i++) {
            int row  = wave * 32 + i * 8 + sRowV;
            int logc = sPhyV ^ (row & 7);
            GLDS16(Vtb + (size_t)row * 2048 + kt * 64 + logc * 8,
                   &Vs[buf][(wave * 32 + i * 8) * 64]);
        }
    };

    stageK(0, 0);
    stageV(0, 0);

    int cur = 0;
    for (int kt = 0; kt <= qb; kt++) {
        __syncthreads();                     // drains vmcnt: buf[cur] ready
        if (kt < qb) { stageK(cur ^ 1, kt + 1); stageV(cur ^ 1, kt + 1); }

        // QK^T: D[m=q(quad*4+r)][n=t(l16)] per 16-token group g
        f32x4 sacc[4];
        __builtin_amdgcn_s_setprio(1);
#pragma unroll
        for (int g = 0; g < 4; g++) {
            sacc[g] = {0.f, 0.f, 0.f, 0.f};
#pragma unroll
            for (int ks = 0; ks < 4; ks++) {
                int row  = l16 + 16 * g;
                int phys = (ks * 4 + quad) ^ l16;
                short8 kf = *(const short8*)(&Ks[cur][row * 128 + phys * 8]);
                sacc[g] = __builtin_amdgcn_mfma_f32_16x16x32_bf16(qf[ks], kf, sacc[g], 0, 0, 0);
            }
        }
        __builtin_amdgcn_s_setprio(0);

        const int srow_base = qb * 64 + wave * 16 + quad * 4;
        const bool diag = (kt == qb);
        float sv[4][4];
#pragma unroll
        for (int g = 0; g < 4; g++)
#pragma unroll
            for (int r = 0; r < 4; r++) {
                float x = sacc[g][r] * scale;
                if (diag) {
                    int t = kt * 64 + g * 16 + l16;
                    if (t > srow_base + r) x = -1e30f;
                }
                sv[g][r] = x;
            }

        float mx[4];
#pragma unroll
        for (int r = 0; r < 4; r++) {
            float m0 = fmaxf(fmaxf(sv[0][r], sv[1][r]), fmaxf(sv[2][r], sv[3][r]));
#pragma unroll
            for (int off = 1; off < 16; off <<= 1)
                m0 = fmaxf(m0, __shfl_xor(m0, off, 64));
            mx[r] = m0;
        }
        // defer-max (T13): skip O-rescale while max growth <= 8
        int grow = 0;
#pragma unroll
        for (int r = 0; r < 4; r++) grow |= (mx[r] > mrow[r] + 8.f) ? 1 : 0;
        if (__any(grow)) {
#pragma unroll
            for (int r = 0; r < 4; r++) {
                float mn = fmaxf(mrow[r], mx[r]);
                float al = __expf(mrow[r] - mn);
                mrow[r] = mn;
                lrow[r] *= al;
#pragma unroll
                for (int gd = 0; gd < 8; gd++) oacc[gd][r] *= al;
            }
        }
#pragma unroll
        for (int r = 0; r < 4; r++) {
            float rs = 0.f;
#pragma unroll
            for (int g = 0; g < 4; g++) {
                float p = __expf(sv[g][r] - mrow[r]);
                sv[g][r] = p;
                rs += p;
            }
#pragma unroll
            for (int off = 1; off < 16; off <<= 1)
                rs += __shfl_xor(rs, off, 64);
            lrow[r] += rs;
        }

        // P: per-wave LDS transpose (Pw[wave] is wave-private -> no barrier)
#pragma unroll
        for (int g = 0; g < 4; g++)
#pragma unroll
            for (int r = 0; r < 4; r++)
                Pw[wave][quad * 4 + r][l16 + 16 * g] = f2bf(sv[g][r]);
        asm volatile("s_waitcnt lgkmcnt(0)" ::: "memory");
        __builtin_amdgcn_sched_barrier(0);

        // PV: D[m=q][n=d(l16+16gd)]
        __builtin_amdgcn_s_setprio(1);
#pragma unroll
        for (int ks = 0; ks < 2; ks++) {
            short8 af = *(const short8*)(&Pw[wave][l16][ks * 32 + quad * 8]);
#pragma unroll
            for (int gd = 0; gd < 8; gd++) {
                int row  = l16 + 16 * gd;
                int phys = (ks * 4 + quad) ^ (l16 & 7);
                short8 vf = *(const short8*)(&Vs[cur][row * 64 + phys * 8]);
                oacc[gd] = __builtin_amdgcn_mfma_f32_16x16x32_bf16(af, vf, oacc[gd], 0, 0, 0);
            }
        }
        __builtin_amdgcn_s_setprio(0);
        cur ^= 1;
    }

    // epilogue: write O in-place into the q-slot (ld 6144)
    const int srow_base = qb * 64 + wave * 16 + quad * 4;
#pragma unroll
    for (int r = 0; r < 4; r++) {
        float inv = 1.0f / lrow[r];
        size_t rowoff = (size_t)(b * 2048 + srow_base + r) * ld + h * 128;
#pragma unroll
        for (int gd = 0; gd < 8; gd++)
            qkv[rowoff + gd * 16 + l16] = f2bf(oacc[gd][r] * inv);
    }
}

// ---------------------------------------------------------------------------
// launcher
// ---------------------------------------------------------------------------
extern "C" void kernel_launch(void* const* d_in, const int* in_sizes, int n_in,
                              void* d_out, int out_size, void* d_ws, size_t ws_size,
                              hipStream_t stream)
{
    const int*   positions = (const int*)d_in[0];
    const float* hidden    = (const float*)d_in[1];  // fp32 [4096, 4096]
    const float* w_qkv     = (const float*)d_in[2];  // fp32 [4096, 6144]
    const float* w_o       = (const float*)d_in[3];  // fp32 [4096, 4096]
    float* out = (float*)d_out;                      // fp32 [4096, 4096]

    short* qkv = (short*)d_ws;                       // bf16 [4096][6144], 48 MB
    short* wT  = qkv + (size_t)4096 * 6144;          // 32 MB transpose buffer
    short* vT  = wT;                                 // 8 MB V^T, aliased (stream-ordered)
    short* hB  = wT + (size_t)4096 * 4096;           // 32 MB hidden bf16 (optional)

    const size_t need = ((size_t)4096 * 6144 + (size_t)4096 * 4096 * 2) * sizeof(short);
    const bool cvtA = (ws_size >= need);

    // 1) QKV projection in two N-chunks of 3072 (wT reused, stream-ordered)
    if (cvtA) {
        cvt_bf16<<<2048, 256, 0, stream>>>(hidden, hB, 4096 * 4096 / 8);
        for (int c = 0; c < 2; c++) {
            transpose_cvt<<<dim3(48, 64), 256, 0, stream>>>(
                w_qkv + c * 3072, 6144, wT, 4096, 3072);
            gemm_tn<short, short><<<dim3(24, 32), 256, 0, stream>>>(
                hB, 4096, wT, qkv + c * 3072, 6144, 4096, 3072, 4096);
        }
    } else {
        for (int c = 0; c < 2; c++) {
            transpose_cvt<<<dim3(48, 64), 256, 0, stream>>>(
                w_qkv + c * 3072, 6144, wT, 4096, 3072);
            gemm_tn<float, short><<<dim3(24, 32), 256, 0, stream>>>(
                hidden, 4096, wT, qkv + c * 3072, 6144, 4096, 3072, 4096);
        }
    }
    // 2) V^T into the (now free) wT region; RoPE in place on q,k
    transpose_v<<<dim3(32, 2, 16), 256, 0, stream>>>(qkv, vT);
    rope_kernel<<<4096, 256, 0, stream>>>(positions, qkv);
    // 3) causal GQA flash attention (output -> q-slot)
    attn_kernel<<<2048, 256, 0, stream>>>(qkv, vT);
    // 4) output projection: A = q-slot of qkv (lda 6144), B = w_o^T
    transpose_cvt<<<dim3(64, 64), 256, 0, stream>>>(w_o, 4096, wT, 4096, 4096);
    gemm_tn<short, float><<<dim3(32, 32), 256, 0, stream>>>(
        qkv, 6144, wT, out, 4096, 4096, 4096, 4096);
}

// Round 3
// 768.131 us; speedup vs baseline: 1.3483x; 1.1987x over previous
//
#include <hip/hip_runtime.h>
#include <stdint.h>
#include <stddef.h>

// ---------------------------------------------------------------------------
// MixtralAttention on MI355X (gfx950).
// fp32 in/out, bf16 MFMA compute. B=2,S=2048,H=4096,NH=32,NKV=8,D=128
// ws layout: qkv [4096][6144] bf16 (48MB) ; wT 32MB (also holds vT 8MB) ;
//            hiddenB 32MB (guarded)
// Attention output written in-place into the q-slot of qkv.
// ---------------------------------------------------------------------------

typedef short short8 __attribute__((ext_vector_type(8)));
typedef short short4v __attribute__((ext_vector_type(4)));
typedef float f32x4  __attribute__((ext_vector_type(4)));

__device__ __forceinline__ float bf2f(short s) {
    union { uint32_t u; float f; } v;
    v.u = ((uint32_t)(uint16_t)s) << 16;
    return v.f;
}
__device__ __forceinline__ short f2bf(float f) {
    union { float f; uint32_t u; } v;
    v.f = f;
    uint32_t u = v.u;
    uint32_t r = (u + 0x7FFFu + ((u >> 16) & 1u)) >> 16;  // RNE
    return (short)(uint16_t)r;
}
__device__ __forceinline__ short8 ldcvt8(const float* p) {
    float4 a = *(const float4*)p;
    float4 b = *(const float4*)(p + 4);
    short8 r;
    r[0] = f2bf(a.x); r[1] = f2bf(a.y); r[2] = f2bf(a.z); r[3] = f2bf(a.w);
    r[4] = f2bf(b.x); r[5] = f2bf(b.y); r[6] = f2bf(b.z); r[7] = f2bf(b.w);
    return r;
}
__device__ __forceinline__ void st_out(short* p, float v) { *p = f2bf(v); }
__device__ __forceinline__ void st_out(float* p, float v) { *p = v; }

#define GLDS16(g, l) __builtin_amdgcn_global_load_lds( \
    (const __attribute__((address_space(1))) void*)(g), \
    (__attribute__((address_space(3))) void*)(l), 16, 0, 0)

// ---------------------------------------------------------------------------
// fp32 -> bf16 bulk convert (grid-stride, 8 elems/thread/iter)
// ---------------------------------------------------------------------------
__global__ __launch_bounds__(256)
void cvt_bf16(const float* __restrict__ in, short* __restrict__ out, int n8)
{
    int i = blockIdx.x * 256 + threadIdx.x;
    int stride = gridDim.x * 256;
    for (; i < n8; i += stride)
        *(short8*)(out + (size_t)i * 8) = ldcvt8(in + (size_t)i * 8);
}

// ---------------------------------------------------------------------------
// Tiled transpose + fp32->bf16 convert: in[R][ldin] (slice width Cs) -> out[Cs][R]
// ---------------------------------------------------------------------------
__global__ __launch_bounds__(256)
void transpose_cvt(const float* __restrict__ in, int ldin,
                   short* __restrict__ out, int R, int Cs)
{
    __shared__ short tile[64][72];
    const int bc = blockIdx.x * 64;   // col base (input)
    const int br = blockIdx.y * 64;   // row base (input)
    const int tid = threadIdx.x;
    const int r  = tid >> 2;          // 0..63
    const int c0 = (tid & 3) * 16;

    const float* src = in + (size_t)(br + r) * ldin + bc + c0;
#pragma unroll
    for (int i = 0; i < 4; i++) {
        float4 v = *(const float4*)(src + 4 * i);
        tile[c0 + 4 * i + 0][r] = f2bf(v.x);
        tile[c0 + 4 * i + 1][r] = f2bf(v.y);
        tile[c0 + 4 * i + 2][r] = f2bf(v.z);
        tile[c0 + 4 * i + 3][r] = f2bf(v.w);
    }
    __syncthreads();

    short* dst = out + (size_t)(bc + r) * R + br + c0;
    *(short8*)(dst)     = *(const short8*)(&tile[r][c0]);
    *(short8*)(dst + 8) = *(const short8*)(&tile[r][c0 + 8]);
}

// ---------------------------------------------------------------------------
// V head-transpose: qkv v-slot [4096 tok][8 hk x 128 d] -> vT[b][hk][128 d][2048 tok]
// ---------------------------------------------------------------------------
__global__ __launch_bounds__(256)
void transpose_v(const short* __restrict__ qkv, short* __restrict__ vT)
{
    __shared__ short tile[64][72];
    const int bh = blockIdx.z;        // b*8 + hk
    const int b  = bh >> 3;
    const int hk = bh & 7;
    const int s0 = blockIdx.x * 64;
    const int d0 = blockIdx.y * 64;
    const int tid = threadIdx.x;
    const int r  = tid >> 2;          // 0..63
    const int c0 = (tid & 3) * 16;

    const short* src = qkv + (size_t)(b * 2048 + s0 + r) * 6144 + 5120 + hk * 128 + d0 + c0;
    short8 v0 = *(const short8*)(src);
    short8 v1 = *(const short8*)(src + 8);
#pragma unroll
    for (int i = 0; i < 8; i++) tile[c0 + i][r] = v0[i];
#pragma unroll
    for (int i = 0; i < 8; i++) tile[c0 + 8 + i][r] = v1[i];
    __syncthreads();

    short* dst = vT + ((size_t)bh * 128 + d0 + r) * 2048 + s0 + c0;
    *(short8*)(dst)     = *(const short8*)(&tile[r][c0]);
    *(short8*)(dst + 8) = *(const short8*)(&tile[r][c0 + 8]);
}

// ---------------------------------------------------------------------------
// Staging helpers for GEMM. LDS tile layout: T[128][64] bf16, XOR-swizzled:
// element (row, chunk16B c_log) lives at byte row*128 + (c_log ^ (row&7))*16.
// ---------------------------------------------------------------------------
__device__ __forceinline__ void stage_tile(const float* __restrict__ Ab, size_t lda,
                                           int kb, short* T, int tid)
{
    const int aRow = tid >> 3;        // 0..31 (+32*j)
    const int aChk = tid & 7;
#pragma unroll
    for (int j = 0; j < 4; j++) {
        int row = aRow + 32 * j;
        short8 v = ldcvt8(Ab + (size_t)row * lda + kb + aChk * 8);
        *(short8*)(&T[row * 64 + ((aChk ^ (row & 7)) * 8)]) = v;
    }
}
__device__ __forceinline__ void stage_tile(const short* __restrict__ Ab, size_t lda,
                                           int kb, short* T, int tid)
{
    const int lane = tid & 63;
    const int wave = tid >> 6;
    const int sRow = lane >> 3;       // 0..7
    const int sPhy = lane & 7;
    const int logc = sPhy ^ sRow;     // (row&7)==sRow for all j
#pragma unroll
    for (int j = 0; j < 4; j++) {
        int row = wave * 32 + j * 8 + sRow;
        const short* g = Ab + (size_t)row * lda + kb + logc * 8;
        GLDS16(g, T + (size_t)(wave * 32 + j * 8) * 64);
    }
}

// ---------------------------------------------------------------------------
// GEMM: C[M,N] = A[M,K] @ Bt[N,K]^T.  A: fp32 (convert) or bf16; Bt bf16
// pre-transposed [N][K]; C fp32 or bf16 with row stride ldc.
// Block 256 = 4 waves (2x2), tile 128x128, BK=64, mfma 16x16x32 bf16.
// ---------------------------------------------------------------------------
template <typename AT, typename CT>
__global__ __launch_bounds__(256, 2)
void gemm_tn(const AT* __restrict__ A, int lda, const short* __restrict__ Bt,
             CT* __restrict__ C, int ldc, int M, int N, int K)
{
    __shared__ __align__(16) short As[128 * 64];
    __shared__ __align__(16) short Bs[128 * 64];

    const int tid  = threadIdx.x;
    const int lane = tid & 63;
    const int wave = tid >> 6;
    const int l16  = lane & 15;
    const int quad = lane >> 4;
    const int wm   = wave >> 1;
    const int wn   = wave & 1;

    // XCD swizzle: contiguous chunk of the row-major (mb,nb) space per XCD
    const int nbx = gridDim.x;
    const int nwg = nbx * gridDim.y;
    int wg = blockIdx.y * nbx + blockIdx.x;
    if ((nwg & 7) == 0) {
        const int cpx = nwg >> 3;
        wg = (wg & 7) * cpx + (wg >> 3);
    }
    const int mb = wg / nbx;
    const int nb = wg - mb * nbx;

    const AT*    Ab = A  + (size_t)mb * 128 * lda;
    const short* Bb = Bt + (size_t)nb * 128 * K;

    f32x4 acc[4][4];
#pragma unroll
    for (int i = 0; i < 4; i++)
#pragma unroll
        for (int j = 0; j < 4; j++) acc[i][j] = {0.f, 0.f, 0.f, 0.f};

    for (int kb = 0; kb < K; kb += 64) {
        __syncthreads();
        stage_tile(Ab, (size_t)lda, kb, As, tid);
        stage_tile(Bb, (size_t)K,   kb, Bs, tid);
        __syncthreads();

#pragma unroll
        for (int ks = 0; ks < 2; ks++) {
            short8 af[4], bf[4];
#pragma unroll
            for (int t = 0; t < 4; t++) {
                int ar = wm * 64 + t * 16 + l16;
                int br = wn * 64 + t * 16 + l16;
                af[t] = *(const short8*)(&As[ar * 64 + (((ks * 4 + quad) ^ (ar & 7)) * 8)]);
                bf[t] = *(const short8*)(&Bs[br * 64 + (((ks * 4 + quad) ^ (br & 7)) * 8)]);
            }
#pragma unroll
            for (int mt = 0; mt < 4; mt++)
#pragma unroll
                for (int nt = 0; nt < 4; nt++)
                    acc[mt][nt] = __builtin_amdgcn_mfma_f32_16x16x32_bf16(
                        af[mt], bf[nt], acc[mt][nt], 0, 0, 0);
        }
    }

#pragma unroll
    for (int mt = 0; mt < 4; mt++)
#pragma unroll
        for (int nt = 0; nt < 4; nt++)
#pragma unroll
            for (int r = 0; r < 4; r++) {
                int row = mb * 128 + wm * 64 + mt * 16 + quad * 4 + r;
                int col = nb * 128 + wn * 64 + nt * 16 + l16;
                st_out(&C[(size_t)row * ldc + col], acc[mt][nt][r]);
            }
}

// ---------------------------------------------------------------------------
// RoPE (neox) in-place on q (32 heads) and k (8 heads) in bf16 qkv ws.
// ---------------------------------------------------------------------------
__global__ __launch_bounds__(256)
void rope_kernel(const int* __restrict__ positions, short* __restrict__ qkv)
{
    const int tok = blockIdx.x;
    const float fp = (float)positions[tok];
    short* base = qkv + (size_t)tok * 6144;
    const float c0 = 0.14391156516f;  // ln(10000)/64

    const int d = threadIdx.x & 63;
    const float inv = __expf(-(float)d * c0);
    const float ang = fp * inv;
    float s, c;
    __sincosf(ang, &s, &c);

    for (int head = threadIdx.x >> 6; head < 40; head += 4) {
        int off = (head < 32) ? head * 128 : 4096 + (head - 32) * 128;
        float x1 = bf2f(base[off + d]);
        float x2 = bf2f(base[off + d + 64]);
        base[off + d]      = f2bf(x1 * c - x2 * s);
        base[off + d + 64] = f2bf(x2 * c + x1 * s);
    }
}

// ---------------------------------------------------------------------------
// Causal GQA flash attention with SWAPPED QK^T (in-register softmax) and
// causal q-tile PAIRING: block handles q-tiles p and 31-p (uniform work).
// Output written IN-PLACE into the q-slot.
// Grid: b(2) x h(32) x pair(16) = 1024 blocks. Block: 4 waves x 16 q-rows/tile.
// K LDS: [64 tok][128 d], chunk16B swizzle c^(row&15).
// V LDS: [128 d][64 tok] from pre-transposed vT, chunk swizzle c^(row&7).
// Swapped QK: sacc[g] = mfma(kf, qf) -> D[m=token g*16+quad*4+r][n=qrow l16].
// Each lane holds 16 token-scores for ONE q-row -> reg-local max/sum,
// only 2 shfl_xor (16,32) per reduce. m/l are per-lane scalars.
// ---------------------------------------------------------------------------
__device__ __forceinline__ void attn_tile(
    const short* __restrict__ Ksb, const short* __restrict__ Vsb,
    short* __restrict__ PwW, const short8 qf[4], f32x4 oacc[8],
    float& mrow, float& lrow, int tok0, int qrow, bool diag,
    int l16, int quad)
{
    const float scale = 0.08838834764831845f;  // 1/sqrt(128)

    f32x4 sacc[4];
    __builtin_amdgcn_s_setprio(1);
#pragma unroll
    for (int g = 0; g < 4; g++) {
        sacc[g] = {0.f, 0.f, 0.f, 0.f};
#pragma unroll
        for (int ks = 0; ks < 4; ks++) {
            int row  = l16 + 16 * g;
            int phys = (ks * 4 + quad) ^ l16;
            short8 kf = *(const short8*)(&Ksb[row * 128 + phys * 8]);
            // swapped operands: A=K (m=token), B=Q (n=qrow)
            sacc[g] = __builtin_amdgcn_mfma_f32_16x16x32_bf16(kf, qf[ks], sacc[g], 0, 0, 0);
        }
    }
    __builtin_amdgcn_s_setprio(0);

    // scale + causal mask (in-register; token = tok0 + g*16 + quad*4 + r)
    float sv[4][4];
    float mx = -1e30f;
#pragma unroll
    for (int g = 0; g < 4; g++)
#pragma unroll
        for (int r = 0; r < 4; r++) {
            float x = sacc[g][r] * scale;
            if (diag) {
                int t = tok0 + g * 16 + quad * 4 + r;
                if (t > qrow) x = -1e30f;
            }
            sv[g][r] = x;
            mx = fmaxf(mx, x);
        }
    mx = fmaxf(mx, __shfl_xor(mx, 16, 64));
    mx = fmaxf(mx, __shfl_xor(mx, 32, 64));

    // defer-max (T13): rescale O only when max grew by > 8
    if (__any(mx > mrow + 8.f)) {
        float mn = fmaxf(mrow, mx);
        float al = __expf(mrow - mn);
        mrow = mn;
        lrow *= al;
#pragma unroll
        for (int r = 0; r < 4; r++) {
            float alr = __shfl(al, quad * 4 + r, 64);
#pragma unroll
            for (int gd = 0; gd < 8; gd++) oacc[gd][r] *= alr;
        }
    }

    float rs = 0.f;
#pragma unroll
    for (int g = 0; g < 4; g++)
#pragma unroll
        for (int r = 0; r < 4; r++) {
            float p = __expf(sv[g][r] - mrow);
            sv[g][r] = p;
            rs += p;
        }
    rs += __shfl_xor(rs, 16, 64);
    rs += __shfl_xor(rs, 32, 64);
    lrow += rs;

    // P -> Pw[qrow=l16][token]: 4 packed ds_write_b64 (r-contiguous)
#pragma unroll
    for (int g = 0; g < 4; g++) {
        short4v pk;
        pk[0] = f2bf(sv[g][0]); pk[1] = f2bf(sv[g][1]);
        pk[2] = f2bf(sv[g][2]); pk[3] = f2bf(sv[g][3]);
        *(short4v*)(&PwW[l16 * 72 + g * 16 + quad * 4]) = pk;
    }
    asm volatile("s_waitcnt lgkmcnt(0)" ::: "memory");
    __builtin_amdgcn_sched_barrier(0);

    // PV: D[m=qrow quad*4+r][n=d l16+16gd]
    __builtin_amdgcn_s_setprio(1);
#pragma unroll
    for (int ks = 0; ks < 2; ks++) {
        short8 af = *(const short8*)(&PwW[l16 * 72 + ks * 32 + quad * 8]);
#pragma unroll
        for (int gd = 0; gd < 8; gd++) {
            int row  = l16 + 16 * gd;
            int phys = (ks * 4 + quad) ^ (l16 & 7);
            short8 vf = *(const short8*)(&Vsb[row * 64 + phys * 8]);
            oacc[gd] = __builtin_amdgcn_mfma_f32_16x16x32_bf16(af, vf, oacc[gd], 0, 0, 0);
        }
    }
    __builtin_amdgcn_s_setprio(0);
}

__global__ __launch_bounds__(256, 2)
void attn_kernel(short* __restrict__ qkv, const short* __restrict__ vT)
{
    __shared__ __align__(16) short Ks[2][64 * 128];
    __shared__ __align__(16) short Vs[2][128 * 64];
    __shared__ __align__(16) short Pw[4][16][72];

    const int blk = blockIdx.x;       // b(2) x h(32) x p(16)
    const int p   = blk & 15;
    const int h   = (blk >> 4) & 31;
    const int b   = blk >> 9;
    const int hk  = h >> 2;
    const int qbL = p;
    const int qbH = 31 - p;

    const int tid  = threadIdx.x;
    const int lane = tid & 63;
    const int wave = tid >> 6;
    const int l16  = lane & 15;
    const int quad = lane >> 4;

    const size_t ld = 6144;
    const short* Kbase = qkv + (size_t)b * 2048 * ld + 4096 + hk * 128;
    const short* Vtb   = vT + (size_t)(b * 8 + hk) * 128 * 2048;
    short* PwW = &Pw[wave][0][0];

    // Q fragments for both q-tiles: B-frag[k = ks*32 + quad*8 + j][n=l16]
    short8 qfL[4], qfH[4];
    {
        const short* QpL = qkv + (size_t)(b * 2048 + qbL * 64 + wave * 16 + l16) * ld + h * 128;
        const short* QpH = qkv + (size_t)(b * 2048 + qbH * 64 + wave * 16 + l16) * ld + h * 128;
#pragma unroll
        for (int ks = 0; ks < 4; ks++) {
            qfL[ks] = *(const short8*)(QpL + ks * 32 + quad * 8);
            qfH[ks] = *(const short8*)(QpH + ks * 32 + quad * 8);
        }
    }

    f32x4 oaccL[8], oaccH[8];
#pragma unroll
    for (int g = 0; g < 8; g++) { oaccL[g] = {0.f,0.f,0.f,0.f}; oaccH[g] = {0.f,0.f,0.f,0.f}; }
    float mL = -1e30f, lL = 0.f, mH = -1e30f, lH = 0.f;

    const int qrowL = qbL * 64 + wave * 16 + l16;
    const int qrowH = qbH * 64 + wave * 16 + l16;

    const int sRowK = lane >> 4;   // 0..3
    const int sPhyK = lane & 15;
    const int sRowV = lane >> 3;   // 0..7
    const int sPhyV = lane & 7;

    auto stageK = [&](int buf, int kt) {
#pragma unroll
        for (int i = 0; i < 4; i++) {
            int row  = wave * 16 + i * 4 + sRowK;
            int logc = sPhyK ^ (row & 15);
            GLDS16(Kbase + (size_t)(kt * 64 + row) * ld + logc * 8,
                   &Ks[buf][(wave * 16 + i * 4) * 128]);
        }
    };
    auto stageV = [&](int buf, int kt) {
#pragma unroll
        for (int i = 0; i < 4; i++) {
            int row  = wave * 32 + i * 8 + sRowV;
            int logc = sPhyV ^ (row & 7);
            GLDS16(Vtb + (size_t)row * 2048 + kt * 64 + logc * 8,
                   &Vs[buf][(wave * 32 + i * 8) * 64]);
        }
    };

    stageK(0, 0);
    stageV(0, 0);

    int cur = 0;
    for (int kt = 0; kt <= qbH; kt++) {
        __syncthreads();                     // drains vmcnt: buf[cur] ready
        if (kt < qbH) { stageK(cur ^ 1, kt + 1); stageV(cur ^ 1, kt + 1); }

        attn_tile(&Ks[cur][0], &Vs[cur][0], PwW, qfH, oaccH, mH, lH,
                  kt * 64, qrowH, kt == qbH, l16, quad);
        if (kt <= qbL)
            attn_tile(&Ks[cur][0], &Vs[cur][0], PwW, qfL, oaccL, mL, lL,
                      kt * 64, qrowL, kt == qbL, l16, quad);
        cur ^= 1;
    }

    // epilogue: write O in-place into the q-slot (ld 6144)
#pragma unroll
    for (int r = 0; r < 4; r++) {
        float liH = 1.0f / __shfl(lH, quad * 4 + r, 64);
        float liL = 1.0f / __shfl(lL, quad * 4 + r, 64);
        size_t rowH = (size_t)(b * 2048 + qbH * 64 + wave * 16 + quad * 4 + r) * ld + h * 128;
        size_t rowL = (size_t)(b * 2048 + qbL * 64 + wave * 16 + quad * 4 + r) * ld + h * 128;
#pragma unroll
        for (int gd = 0; gd < 8; gd++) {
            qkv[rowH + gd * 16 + l16] = f2bf(oaccH[gd][r] * liH);
            qkv[rowL + gd * 16 + l16] = f2bf(oaccL[gd][r] * liL);
        }
    }
}

// ---------------------------------------------------------------------------
// launcher
// ---------------------------------------------------------------------------
extern "C" void kernel_launch(void* const* d_in, const int* in_sizes, int n_in,
                              void* d_out, int out_size, void* d_ws, size_t ws_size,
                              hipStream_t stream)
{
    const int*   positions = (const int*)d_in[0];
    const float* hidden    = (const float*)d_in[1];  // fp32 [4096, 4096]
    const float* w_qkv     = (const float*)d_in[2];  // fp32 [4096, 6144]
    const float* w_o       = (const float*)d_in[3];  // fp32 [4096, 4096]
    float* out = (float*)d_out;                      // fp32 [4096, 4096]

    short* qkv = (short*)d_ws;                       // bf16 [4096][6144], 48 MB
    short* wT  = qkv + (size_t)4096 * 6144;          // 32 MB transpose buffer
    short* vT  = wT;                                 // 8 MB V^T, aliased (stream-ordered)
    short* hB  = wT + (size_t)4096 * 4096;           // 32 MB hidden bf16 (optional)

    const size_t need = ((size_t)4096 * 6144 + (size_t)4096 * 4096 * 2) * sizeof(short);
    const bool cvtA = (ws_size >= need);

    // 1) QKV projection in two N-chunks of 3072 (wT reused, stream-ordered)
    if (cvtA) {
        cvt_bf16<<<2048, 256, 0, stream>>>(hidden, hB, 4096 * 4096 / 8);
        for (int c = 0; c < 2; c++) {
            transpose_cvt<<<dim3(48, 64), 256, 0, stream>>>(
                w_qkv + c * 3072, 6144, wT, 4096, 3072);
            gemm_tn<short, short><<<dim3(24, 32), 256, 0, stream>>>(
                hB, 4096, wT, qkv + c * 3072, 6144, 4096, 3072, 4096);
        }
    } else {
        for (int c = 0; c < 2; c++) {
            transpose_cvt<<<dim3(48, 64), 256, 0, stream>>>(
                w_qkv + c * 3072, 6144, wT, 4096, 3072);
            gemm_tn<float, short><<<dim3(24, 32), 256, 0, stream>>>(
                hidden, 4096, wT, qkv + c * 3072, 6144, 4096, 3072, 4096);
        }
    }
    // 2) V^T into the (now free) wT region; RoPE in place on q,k
    transpose_v<<<dim3(32, 2, 16), 256, 0, stream>>>(qkv, vT);
    rope_kernel<<<4096, 256, 0, stream>>>(positions, qkv);
    // 3) causal GQA flash attention (paired q-tiles, output -> q-slot)
    attn_kernel<<<1024, 256, 0, stream>>>(qkv, vT);
    // 4) output projection: A = q-slot of qkv (lda 6144), B = w_o^T
    transpose_cvt<<<dim3(64, 64), 256, 0, stream>>>(w_o, 4096, wT, 4096, 4096);
    gemm_tn<short, float><<<dim3(32, 32), 256, 0, stream>>>(
        qkv, 6144, wT, out, 4096, 4096, 4096, 4096);
}